// Round 17
// baseline (327.065 us; speedup 1.0000x reference)
//
#include <hip/hip_runtime.h>
#include <hip/hip_bf16.h>

// Problem constants (from setup_inputs)
#define N_EMB   6272
#define N_PAD   6400     // A rows padded to multiple of 256 (pad rows harmless)
#define M_BANK  32768
#define D_DIM   128
#define KPA     128      // A packed: [hi(128)]  (pure bf16)
#define KPB     128      // B packed: [hi(128)]
#define BATCH   8
#define P_PATCH 784      // 6272 / 8
#define GRID_WH 28
#define OUT_WH  224
#define KNN     9
#define KSIZE   33
#define KRAD    16

typedef unsigned long long ull;
typedef short bf16x8 __attribute__((ext_vector_type(8)));
typedef float f32x4  __attribute__((ext_vector_type(4)));

// ---------------- workspace layout (bytes), ws ~256 MB ----------------
#define WS_MINPACK 0          // u64[6400]            -> 51200 (pad slack incl.)
#define WS_X2      51200     // f32[6272]             -> 76288
#define WS_Y2      76288     // f32[32768]            -> 207360
#define WS_BSCORE  207360    // f32[8]
#define WS_BMAXP   207392    // i32[8]
#define WS_BNN     207424    // i32[8]
#define WS_DNN     207488    // f32[8*32768]          -> 1256064
#define WS_APK     1256064   // u16[6400*128]         -> 2894464  (16B aligned)
#define WS_BPK     2894464   // u16[32768*128]        -> 11283072 (16B aligned)
#define WS_CAND    11283072  // u64[8*32*9]           -> 11301504

__device__ __forceinline__ ull umin64(ull a, ull b) { return a < b ? a : b; }
__device__ __forceinline__ ull umax64(ull a, ull b) { return a > b ? a : b; }

__device__ __forceinline__ void gload_lds16(const void* g, void* l) {
    __builtin_amdgcn_global_load_lds(
        (const __attribute__((address_space(1))) void*)g,
        (__attribute__((address_space(3))) void*)l, 16, 0, 0);
}

// last-block ticket for the fused topk final phase (256 blocks only —
// R15 lesson: per-block __threadfence is catastrophic on LARGE grids)
__device__ unsigned tpf_ctr = 0;

// ---------------------------------------------------------------------------
// Kernel 0 (prep): per-row bf16 pack (hi only, pure bf16) + sum-of-squares
// + minpack init. One wave per row. (Apk pad rows 6272..6399 never written —
// constant workspace bytes; analyzed harmless: pad keys can only lose umin
// and land in minpack pad slack, never read.)
// ---------------------------------------------------------------------------
__global__ __launch_bounds__(256) void prep_kernel(
    const float* __restrict__ emb, const float* __restrict__ bank,
    unsigned short* __restrict__ Apk, unsigned short* __restrict__ Bpk,
    float* __restrict__ x2, float* __restrict__ y2, ull* __restrict__ minpack)
{
    const int tid = threadIdx.x;
    int gi = blockIdx.x * 256 + tid;
    if (gi < N_EMB) minpack[gi] = ~0ull;

    const int w    = blockIdx.x * 4 + (tid >> 6);
    const int lane = tid & 63;

    const float* src;
    unsigned short* dst;
    float* sq;
    if (w < N_EMB) {
        src = emb + (size_t)w * D_DIM;
        dst = Apk + (size_t)w * KPA;
        sq  = x2 + w;
    } else {
        int m = w - N_EMB;             // grid sized exactly -> m < M_BANK
        src = bank + (size_t)m * D_DIM;
        dst = Bpk + (size_t)m * KPB;
        sq  = y2 + m;
    }
    float2 v = *(const float2*)&src[2 * lane];
    __hip_bfloat16 h0 = __float2bfloat16(v.x);
    __hip_bfloat16 h1 = __float2bfloat16(v.y);
    unsigned hb0 = *(unsigned short*)&h0, hb1 = *(unsigned short*)&h1;
    *(unsigned*)&dst[2 * lane] = hb0 | (hb1 << 16);

    float s = fmaf(v.x, v.x, v.y * v.y);
    #pragma unroll
    for (int off = 32; off > 0; off >>= 1) s += __shfl_down(s, off, 64);
    if (lane == 0) *sq = s;
}

// ---------------------------------------------------------------------------
// Kernel 1: MFMA distance + fused min/argmin — 8-wave 256x128 block.
// Wave tile 64x64 (acc[4][4]) — per-wave work identical to the proven R14
// kernel; block covers 2x the A rows -> 16 waves/CU resident (vs ~10.7),
// per-output barrier + B-staging cost halved. LDS 48 KB: A dbuf 2x16KB +
// B dbuf 2x8KB. Staging: 3 gloads/thread/chunk (A row srow, srow+128; B row
// srow), vmcnt(3) steady. Race fix (R14): lgkmcnt(0)+sched_barrier before
// barrier#1. Epilogue in two 128-row phases over a 32 KB red2 overlay.
// Grid: 256 x 25 (A padded to 6400 rows; pad analyzed harmless).
// ---------------------------------------------------------------------------
__global__ __launch_bounds__(512, 4) void mfma_min_kernel(
    const unsigned short* __restrict__ Apk, const unsigned short* __restrict__ Bpk,
    const float* __restrict__ y2, ull* __restrict__ minpack)
{
    __shared__ __align__(16) unsigned short smem[2 * 256 * 32 + 2 * 128 * 32]; // 48 KB
    const int APAN = 256 * 32;       // 8192 elems = 16 KB panel
    const int BPAN = 128 * 32;       // 4096 elems = 8 KB panel
    const int BOFF = 2 * APAN;       // B panels base

    const int tid  = threadIdx.x;
    const int lane = tid & 63;
    const int wave = tid >> 6;       // 0..7
    const int wr = wave >> 1;        // 0..3 (A row quadrant)
    const int wc = wave & 1;         // 0..1 (B col half)
    const int n0 = blockIdx.y * 256;
    const int m0 = blockIdx.x * 128;

    const int srow = tid >> 2;   // 0..127 staging base row
    const int sseg = tid & 3;    // 16B segment (LDS phys)
    const int ssw  = sseg ^ ((srow >> 1) & 3);   // swizzled GLOBAL segment
                                                 // (same key for srow+128)

    const int qa = lane >> 4;    // k-quad (logical)
    const int ra = lane & 15;    // row-in-frag / col-in-C
    const int qsw = qa ^ ((ra >> 1) & 3);        // swizzled LDS segment to read

    f32x4 acc[4][4];
    #pragma unroll
    for (int i = 0; i < 4; ++i)
        #pragma unroll
        for (int j = 0; j < 4; ++j)
            acc[i][j] = (f32x4){0.f, 0.f, 0.f, 0.f};

    const unsigned short* gA = Apk + (size_t)(n0 + srow) * KPA + ssw * 8;
    const unsigned short* gB = Bpk + (size_t)(m0 + srow) * KPB + ssw * 8;
    const int lof0 = srow * 32 + sseg * 8;            // linear LDS dests
    const int lof1 = (srow + 128) * 32 + sseg * 8;    // A second half

    // prologue: chunk 0 -> buffer 0 (3 loads/thread)
    gload_lds16(gA,             &smem[lof0]);
    gload_lds16(gA + 128 * KPA, &smem[lof1]);
    gload_lds16(gB,             &smem[BOFF + lof0]);

    #define STEP(s, VM) { \
        /* drain this wave's LDS reads before other waves overwrite (R14) */ \
        asm volatile("s_waitcnt lgkmcnt(0)" ::: "memory"); \
        __builtin_amdgcn_sched_barrier(0); \
        asm volatile("s_barrier" ::: "memory"); \
        if ((s) < 3) { \
            const int ko = ((s) + 1) * 32; \
            const int nb = ((s) + 1) & 1; \
            gload_lds16(gA + ko,             &smem[nb * APAN + lof0]); \
            gload_lds16(gA + ko + 128 * KPA, &smem[nb * APAN + lof1]); \
            gload_lds16(gB + ko,             &smem[BOFF + nb * BPAN + lof0]); \
        } \
        asm volatile("s_waitcnt vmcnt(" #VM ")" ::: "memory"); \
        asm volatile("s_barrier" ::: "memory"); \
        const unsigned short* As = &smem[((s) & 1) * APAN]; \
        const unsigned short* Bs = &smem[BOFF + ((s) & 1) * BPAN]; \
        bf16x8 bfr[4]; \
        _Pragma("unroll") \
        for (int j = 0; j < 4; ++j) \
            bfr[j] = *(const bf16x8*)&Bs[(wc * 64 + j * 16 + ra) * 32 + qsw * 8]; \
        { \
            bf16x8 af0 = *(const bf16x8*)&As[(wr * 64 +  0 + ra) * 32 + qsw * 8]; \
            bf16x8 af1 = *(const bf16x8*)&As[(wr * 64 + 16 + ra) * 32 + qsw * 8]; \
            _Pragma("unroll") \
            for (int j = 0; j < 4; ++j) \
                acc[0][j] = __builtin_amdgcn_mfma_f32_16x16x32_bf16(af0, bfr[j], acc[0][j], 0, 0, 0); \
            _Pragma("unroll") \
            for (int j = 0; j < 4; ++j) \
                acc[1][j] = __builtin_amdgcn_mfma_f32_16x16x32_bf16(af1, bfr[j], acc[1][j], 0, 0, 0); \
            __builtin_amdgcn_sched_barrier(0); \
            bf16x8 af2 = *(const bf16x8*)&As[(wr * 64 + 32 + ra) * 32 + qsw * 8]; \
            bf16x8 af3 = *(const bf16x8*)&As[(wr * 64 + 48 + ra) * 32 + qsw * 8]; \
            _Pragma("unroll") \
            for (int j = 0; j < 4; ++j) \
                acc[2][j] = __builtin_amdgcn_mfma_f32_16x16x32_bf16(af2, bfr[j], acc[2][j], 0, 0, 0); \
            _Pragma("unroll") \
            for (int j = 0; j < 4; ++j) \
                acc[3][j] = __builtin_amdgcn_mfma_f32_16x16x32_bf16(af3, bfr[j], acc[3][j], 0, 0, 0); \
        } \
    }

    STEP(0, 3) STEP(1, 3) STEP(2, 3) STEP(3, 0)
    #undef STEP

    // ---- epilogue: key = y2[m]+1000 - 2*dot (R11-proven exprs), two phases ----
    float y2k[4];
    unsigned mj[4];
    #pragma unroll
    for (int j = 0; j < 4; ++j) {
        const int m = m0 + wc * 64 + j * 16 + ra;
        y2k[j] = y2[m] + 1000.0f;
        mj[j]  = (unsigned)m;
    }

    ull (*red2)[32] = (ull (*)[32])smem;   // 128 rows x 32 = 32 KB overlay

    // all waves must be done reading the K-panels before red2 overwrites them
    __syncthreads();

    // phase 1: A rows 0..127 (waves with wr < 2)
    if (wr < 2) {
        #pragma unroll
        for (int i = 0; i < 4; ++i) {
            #pragma unroll
            for (int r = 0; r < 4; ++r) {
                const int rowl = wr * 64 + i * 16 + qa * 4 + r;   // 0..127
                ull mn = ~0ull;
                #pragma unroll
                for (int j = 0; j < 4; ++j) {
                    float key = fmaf(-2.0f, acc[i][j][r], y2k[j]);
                    ull p = ((ull)__float_as_uint(key) << 32) | mj[j];
                    mn = umin64(mn, p);
                }
                red2[rowl][wc * 16 + ra] = mn;
            }
        }
    }
    __syncthreads();
    if (tid < 128) {
        const int l = tid & 63;
        ull mn = ~0ull;
        #pragma unroll
        for (int k = 0; k < 32; ++k)
            mn = umin64(mn, red2[tid][(k + l) & 31]);
        atomicMin(&minpack[n0 + tid], mn);
    }
    __syncthreads();

    // phase 2: A rows 128..255 (waves with wr >= 2)
    if (wr >= 2) {
        #pragma unroll
        for (int i = 0; i < 4; ++i) {
            #pragma unroll
            for (int r = 0; r < 4; ++r) {
                const int rowl = (wr - 2) * 64 + i * 16 + qa * 4 + r;  // 0..127
                ull mn = ~0ull;
                #pragma unroll
                for (int j = 0; j < 4; ++j) {
                    float key = fmaf(-2.0f, acc[i][j][r], y2k[j]);
                    ull p = ((ull)__float_as_uint(key) << 32) | mj[j];
                    mn = umin64(mn, p);
                }
                red2[rowl][wc * 16 + ra] = mn;
            }
        }
    }
    __syncthreads();
    if (tid < 128) {
        const int l = tid & 63;
        ull mn = ~0ull;
        #pragma unroll
        for (int k = 0; k < 32; ++k)
            mn = umin64(mn, red2[tid][(k + l) & 31]);
        atomicMin(&minpack[n0 + 128 + tid], mn);
    }
}

// ---------------------------------------------------------------------------
// Kernel 2: tiny per-batch argmax (1 block; wave w handles batches w, w+4).
// ---------------------------------------------------------------------------
__global__ __launch_bounds__(256) void argmax_kernel(
    const ull* __restrict__ minpack, const float* __restrict__ x2,
    float* __restrict__ bscore, int* __restrict__ bmaxp, int* __restrict__ bnn)
{
    const int tid = threadIdx.x;
    const int wv = tid >> 6, ln = tid & 63;
    #pragma unroll
    for (int half = 0; half < 2; ++half) {
        const int bb = wv + half * 4;
        ull best = 0;
        for (int i = ln; i < P_PATCH; i += 64) {
            ull mp = minpack[bb * P_PATCH + i];
            float key = __uint_as_float((unsigned)(mp >> 32));
            float d2 = key - 1000.0f + x2[bb * P_PATCH + i];
            float sc = sqrtf(fmaxf(d2, 0.0f));
            ull pk = ((ull)__float_as_uint(sc) << 32) | (unsigned)(i ^ 0xFFFFFFFFu);
            best = umax64(best, pk);
        }
        #pragma unroll
        for (int s = 1; s < 64; s <<= 1)
            best = umax64(best, (ull)__shfl_xor((unsigned long long)best, s, 64));
        if (ln == 0) {
            int p = (int)(((unsigned)(best & 0xFFFFFFFFu)) ^ 0xFFFFFFFFu);
            bscore[bb] = __uint_as_float((unsigned)(best >> 32));
            bmaxp[bb]  = p;
            bnn[bb]    = (int)(minpack[bb * P_PATCH + p] & 0xFFFFFFFFu);
        }
    }
}

// ---------------------------------------------------------------------------
// Kernel 3: d_nn = dist(nn_sample[b], memory_bank) -> (8, M)
// (8192 blocks, fully parallel, BW-bound; depends only on bnn)
// ---------------------------------------------------------------------------
__global__ __launch_bounds__(256) void dnn_kernel(
    const float* __restrict__ bank, const float* __restrict__ y2,
    const int* __restrict__ bnn, float* __restrict__ dnn)
{
    __shared__ float nn[BATCH][D_DIM];
    __shared__ float nny2[BATCH];
    int tid = threadIdx.x;
    for (int i = tid; i < BATCH * D_DIM; i += 256) {
        int b = i >> 7, d = i & 127;
        nn[b][d] = bank[(size_t)bnn[b] * D_DIM + d];
    }
    if (tid < BATCH) nny2[tid] = y2[bnn[tid]];
    __syncthreads();

    int w = tid >> 6, lane = tid & 63;
    int m = blockIdx.x * 4 + w;
    float2 v = *(const float2*)&bank[(size_t)m * D_DIM + 2 * lane];
    float part[BATCH];
    #pragma unroll
    for (int b = 0; b < BATCH; ++b)
        part[b] = fmaf(v.x, nn[b][2 * lane], v.y * nn[b][2 * lane + 1]);
    #pragma unroll
    for (int b = 0; b < BATCH; ++b) {
        float s = part[b];
        #pragma unroll
        for (int off = 32; off > 0; off >>= 1) s += __shfl_down(s, off, 64);
        if (lane == 0) {
            float d2 = nny2[b] + y2[m] - 2.0f * s;
            dnn[b * M_BANK + m] = sqrtf(fmaxf(d2, 0.0f));
        }
    }
}

// ---------------------------------------------------------------------------
// Kernel 4 (merged blur + topk, proven R15/R16): grid (39, 8). ch<32: per-
// (b,ch) top-9 of d_nn (+ last-block final, 256-block ticket). ch>=32: blur
// band ch-32 for batch b. Block-uniform branch; LDS union.
// ---------------------------------------------------------------------------
__device__ __forceinline__ int refl224(int i) {
    if (i < 0) i = -i;
    if (i >= OUT_WH) i = 2 * (OUT_WH - 1) - i;
    return i;
}

union SharedU {
    struct {
        float g[KSIZE];
        float ps[P_PATCH];
        float q[GRID_WH * OUT_WH];
        float hq[GRID_WH * OUT_WH];
        float wrow[32][GRID_WH];
    } blur;
    struct {
        ull vals[1024];
        ull red[256];
    } topk;
};

__global__ __launch_bounds__(256) void blur_topk_kernel(
    const ull* __restrict__ minpack, const float* __restrict__ x2,
    const float* __restrict__ dnn, ull* __restrict__ cand,
    const float* __restrict__ emb, const float* __restrict__ bank,
    const float* __restrict__ y2,
    const float* __restrict__ bscore, const int* __restrict__ bmaxp,
    float* __restrict__ out)
{
    __shared__ SharedU su;
    __shared__ unsigned lastflag;
    const int tid = threadIdx.x;
    const int b = blockIdx.y;

    if (blockIdx.x < 32) {
        // ---------------- top-9 branch ----------------
        const int ch = blockIdx.x;
        const int base = ch * 1024;
        ull* vals = su.topk.vals;
        ull* red  = su.topk.red;

        #pragma unroll
        for (int j = 0; j < 4; ++j) {
            int i = base + tid + j * 256;
            vals[tid + j * 256] = ((ull)__float_as_uint(dnn[b * M_BANK + i]) << 32) | (unsigned)i;
        }
        __syncthreads();

        for (int k = 0; k < KNN; ++k) {
            ull local = vals[tid];
            #pragma unroll
            for (int j = 1; j < 4; ++j) local = umin64(local, vals[tid + j * 256]);
            red[tid] = local;
            __syncthreads();
            for (int s = 128; s > 0; s >>= 1) {
                if (tid < s) red[tid] = umin64(red[tid], red[tid + s]);
                __syncthreads();
            }
            ull win = red[0];
            if (tid == 0) cand[(b * 32 + ch) * KNN + k] = win;
            #pragma unroll
            for (int j = 0; j < 4; ++j)
                if (vals[tid + j * 256] == win) vals[tid + j * 256] = ~0ull;
            __syncthreads();
        }

        // ---- last-block final phase (ticket over 256 topk blocks) ----
        if (tid == 0) {
            __threadfence();                   // publish this block's cand
            unsigned t = atomicAdd(&tpf_ctr, 1u);
            lastflag = (t == 8u * 32u - 1u);
        }
        __syncthreads();
        if (!lastflag) return;
        __threadfence();                       // acquire all blocks' cand

        const int wv = tid >> 6, ln = tid & 63;
        #pragma unroll
        for (int half = 0; half < 2; ++half) {
            const int bb = wv + half * 4;
            const ull* cb = cand + (size_t)bb * 32 * KNN;   // 288 candidates
            ull c0 = cb[ln];
            ull c1 = cb[ln + 64];
            ull c2 = cb[ln + 128];
            ull c3 = cb[ln + 192];
            ull c4 = (ln < 32) ? cb[ln + 256] : ~0ull;
            const int e = bb * P_PATCH + bmaxp[bb];
            const float mf0 = emb[(size_t)e * D_DIM + 2 * ln];
            const float mf1 = emb[(size_t)e * D_DIM + 2 * ln + 1];
            const float xe = x2[e];
            float dists[KNN];
            #pragma unroll
            for (int k = 0; k < KNN; ++k) {
                ull mn = umin64(umin64(umin64(c0, c1), umin64(c2, c3)), c4);
                #pragma unroll
                for (int s = 1; s < 64; s <<= 1)
                    mn = umin64(mn, (ull)__shfl_xor((unsigned long long)mn, s, 64));
                if (c0 == mn) c0 = ~0ull;
                if (c1 == mn) c1 = ~0ull;
                if (c2 == mn) c2 = ~0ull;
                if (c3 == mn) c3 = ~0ull;
                if (c4 == mn) c4 = ~0ull;
                const int m = (int)(mn & 0xFFFFFFFFu);
                float dot = fmaf(mf0, bank[(size_t)m * D_DIM + 2 * ln],
                                 mf1 * bank[(size_t)m * D_DIM + 2 * ln + 1]);
                #pragma unroll
                for (int s = 1; s < 64; s <<= 1)
                    dot += __shfl_xor(dot, s, 64);
                float d2 = xe - 2.0f * dot + y2[m];
                dists[k] = sqrtf(fmaxf(d2, 0.0f));
            }
            if (ln == 0) {
                float mx = dists[0];
                #pragma unroll
                for (int k = 1; k < KNN; ++k) mx = fmaxf(mx, dists[k]);
                float ssum = 0.0f;
                #pragma unroll
                for (int k = 0; k < KNN; ++k) ssum += expf(dists[k] - mx);
                float wgt = 1.0f - expf(dists[0] - mx) / ssum;
                out[bb] = wgt * bscore[bb];
            }
        }
        if (tid == 0) atomicExch(&tpf_ctr, 0u);    // reset for next replay
        return;
    }

    // ---------------- blur branch ----------------
    const int band = blockIdx.x - 32;     // 0..6
    float* g    = su.blur.g;
    float* ps   = su.blur.ps;
    float* q    = su.blur.q;
    float* hq   = su.blur.hq;
    float (*wrow)[GRID_WH] = su.blur.wrow;
    float* outp = out + BATCH;

    if (tid < KSIZE) {
        float x = (tid - KRAD) * 0.25f;
        g[tid] = __expf(-0.5f * x * x);
    }
    for (int i = tid; i < P_PATCH; i += 256) {
        ull mp = minpack[b * P_PATCH + i];
        float key = __uint_as_float((unsigned)(mp >> 32));
        float d2 = key - 1000.0f + x2[b * P_PATCH + i];
        ps[i] = sqrtf(fmaxf(d2, 0.0f));
    }
    __syncthreads();
    if (tid == 0) {
        float s = 0.0f;
        for (int i = 0; i < KSIZE; ++i) s += g[i];
        float inv = 1.0f / s;
        for (int i = 0; i < KSIZE; ++i) g[i] *= inv;
    }
    __syncthreads();

    for (int i = tid; i < GRID_WH * OUT_WH; i += 256) {
        int gy = i / OUT_WH, x = i - gy * OUT_WH;
        float cx = (2 * x - 7) * 0.0625f;
        int ix = (int)floorf(cx); float fx = cx - ix;
        int x0 = min(max(ix, 0), GRID_WH - 1), x1 = min(max(ix + 1, 0), GRID_WH - 1);
        q[i] = ps[gy * GRID_WH + x0] * (1.0f - fx) + ps[gy * GRID_WH + x1] * fx;
    }

    if (tid < 32) {
        int y = band * 32 + tid;
        for (int gy = 0; gy < GRID_WH; ++gy) wrow[tid][gy] = 0.0f;
        for (int t = 0; t < KSIZE; ++t) {
            int yy = refl224(y - KRAD + t);
            float cy = (2 * yy - 7) * 0.0625f;
            int iy = (int)floorf(cy); float fy = cy - iy;
            int y0 = min(max(iy, 0), GRID_WH - 1), y1 = min(max(iy + 1, 0), GRID_WH - 1);
            wrow[tid][y0] += g[t] * (1.0f - fy);
            wrow[tid][y1] += g[t] * fy;
        }
    }
    __syncthreads();

    for (int i = tid; i < GRID_WH * OUT_WH; i += 256) {
        int gy = i / OUT_WH, x = i - gy * OUT_WH;
        float s = 0.0f;
        #pragma unroll
        for (int t = 0; t < KSIZE; ++t)
            s = fmaf(g[t], q[gy * OUT_WH + refl224(x - KRAD + t)], s);
        hq[i] = s;
    }
    __syncthreads();

    const int yl = tid >> 3;                 // 0..31
    const int xbase = (tid & 7) * 28;        // 8 groups x 28 px = 224
    const int y = band * 32 + yl;
    float* orow = outp + ((size_t)b * OUT_WH + y) * OUT_WH;
    for (int i = 0; i < 28; ++i) {
        int x = xbase + i;
        float s = 0.0f;
        #pragma unroll
        for (int gy = 0; gy < GRID_WH; ++gy)
            s = fmaf(wrow[yl][gy], hq[gy * OUT_WH + x], s);
        orow[x] = s;
    }
}

// ---------------------------------------------------------------------------
extern "C" void kernel_launch(void* const* d_in, const int* in_sizes, int n_in,
                              void* d_out, int out_size, void* d_ws, size_t ws_size,
                              hipStream_t stream) {
    const float* emb  = (const float*)d_in[0];
    const float* bank = (const float*)d_in[1];
    float* out = (float*)d_out;

    char* ws = (char*)d_ws;
    ull*   minpack = (ull*)(ws + WS_MINPACK);
    float* x2      = (float*)(ws + WS_X2);
    float* y2      = (float*)(ws + WS_Y2);
    float* bscore  = (float*)(ws + WS_BSCORE);
    int*   bmaxp   = (int*)(ws + WS_BMAXP);
    int*   bnn     = (int*)(ws + WS_BNN);
    float* dnn     = (float*)(ws + WS_DNN);
    unsigned short* Apk = (unsigned short*)(ws + WS_APK);
    unsigned short* Bpk = (unsigned short*)(ws + WS_BPK);
    ull*   cand    = (ull*)(ws + WS_CAND);

    // 0: bf16 pack + sumsq + minpack init (one wave per row)
    prep_kernel<<<(N_EMB + M_BANK) / 4, 256, 0, stream>>>(emb, bank, Apk, Bpk, x2, y2, minpack);
    // 1: MFMA distance + fused min/argmin (8-wave 256x128 blocks; 256 x 25)
    {
        dim3 grid(M_BANK / 128, N_PAD / 256);   // 256 x 25
        mfma_min_kernel<<<grid, 512, 0, stream>>>(Apk, Bpk, y2, minpack);
    }
    // 2: tiny per-batch argmax (1 block) -> bscore/bmaxp/bnn
    argmax_kernel<<<1, 256, 0, stream>>>(minpack, x2, bscore, bmaxp, bnn);
    // 3: d_nn (8192 blocks, fully parallel)
    dnn_kernel<<<M_BANK / 4, 256, 0, stream>>>(bank, y2, bnn, dnn);
    // 4: merged blur (bands) + per-chunk top-9 + last-block final -> out
    {
        dim3 grid(32 + OUT_WH / 32, BATCH);     // 39 x 8
        blur_topk_kernel<<<grid, 256, 0, stream>>>(minpack, x2, dnn, cand, emb, bank, y2, bscore, bmaxp, out);
    }
}

// Round 18
// 220.329 us; speedup vs baseline: 1.4844x; 1.4844x over previous
//
#include <hip/hip_runtime.h>
#include <hip/hip_bf16.h>

// Problem constants (from setup_inputs)
#define N_EMB   6272
#define M_BANK  32768
#define D_DIM   128
#define KPA     128      // A packed: [hi(128)]  (pure bf16)
#define KPB     128      // B packed: [hi(128)]
#define BATCH   8
#define P_PATCH 784      // 6272 / 8
#define GRID_WH 28
#define OUT_WH  224
#define KNN     9
#define KSIZE   33
#define KRAD    16

typedef unsigned long long ull;
typedef short bf16x8 __attribute__((ext_vector_type(8)));
typedef float f32x4  __attribute__((ext_vector_type(4)));

// ---------------- workspace layout (bytes), ws ~256 MB ----------------
#define WS_MINPACK 0          // u64[6272]            -> 50176
#define WS_X2      50176      // f32[6272]            -> 75264
#define WS_Y2      75264      // f32[32768]           -> 206336
#define WS_BSCORE  231424     // f32[8]
#define WS_BMAXP   231456     // i32[8]
#define WS_BNN     231488     // i32[8]
#define WS_DNN     231552     // f32[8*32768]         -> 1280128
#define WS_APK     2885888    // u16[6272*128]        -> 4491264   (16B aligned)
#define WS_BPK     7702784    // u16[32768*128]       -> 16091392  (16B aligned)
#define WS_CAND    32868608   // u64[8*32*9]          -> 32887040

__device__ __forceinline__ ull umin64(ull a, ull b) { return a < b ? a : b; }
__device__ __forceinline__ ull umax64(ull a, ull b) { return a > b ? a : b; }

__device__ __forceinline__ void gload_lds16(const void* g, void* l) {
    __builtin_amdgcn_global_load_lds(
        (const __attribute__((address_space(1))) void*)g,
        (__attribute__((address_space(3))) void*)l, 16, 0, 0);
}

// last-block ticket for the fused topk final phase (256 blocks only —
// R15 lesson: per-block __threadfence is catastrophic on LARGE grids)
__device__ unsigned tpf_ctr = 0;

// ---------------------------------------------------------------------------
// Kernel 0 (prep): per-row bf16 pack (hi only, pure bf16) + sum-of-squares
// + minpack init. One wave per row.
// ---------------------------------------------------------------------------
__global__ __launch_bounds__(256) void prep_kernel(
    const float* __restrict__ emb, const float* __restrict__ bank,
    unsigned short* __restrict__ Apk, unsigned short* __restrict__ Bpk,
    float* __restrict__ x2, float* __restrict__ y2, ull* __restrict__ minpack)
{
    const int tid = threadIdx.x;
    int gi = blockIdx.x * 256 + tid;
    if (gi < N_EMB) minpack[gi] = ~0ull;

    const int w    = blockIdx.x * 4 + (tid >> 6);
    const int lane = tid & 63;

    const float* src;
    unsigned short* dst;
    float* sq;
    if (w < N_EMB) {
        src = emb + (size_t)w * D_DIM;
        dst = Apk + (size_t)w * KPA;
        sq  = x2 + w;
    } else {
        int m = w - N_EMB;             // grid sized exactly -> m < M_BANK
        src = bank + (size_t)m * D_DIM;
        dst = Bpk + (size_t)m * KPB;
        sq  = y2 + m;
    }
    float2 v = *(const float2*)&src[2 * lane];
    __hip_bfloat16 h0 = __float2bfloat16(v.x);
    __hip_bfloat16 h1 = __float2bfloat16(v.y);
    unsigned hb0 = *(unsigned short*)&h0, hb1 = *(unsigned short*)&h1;
    unsigned hpack = hb0 | (hb1 << 16);
    *(unsigned*)&dst[2 * lane] = hpack;

    float s = fmaf(v.x, v.x, v.y * v.y);
    #pragma unroll
    for (int off = 32; off > 0; off >>= 1) s += __shfl_down(s, off, 64);
    if (lane == 0) *sq = s;
}

// ---------------------------------------------------------------------------
// Kernel 1: MFMA distance + fused min/argmin.  (EXACT R14/R16 proven version)
// 128x128 tile, pure bf16 K=128, 4 steps (32 KB LDS: A dbuf + B dbuf).
// Race fix (R14, proven): lgkmcnt(0)+sched_barrier(0) before barrier#1.
// Epilogue (R11 proven): key = y2[m]+1000 - 2*dot; packed-u64 umin chain.
// Local optimum verified across: tile shape (R3/R4), K structure (R5/R11),
// LDS size (R5), occupancy cap (R6/R8/R17), epilogue form (R12), sync (R13/14).
// ---------------------------------------------------------------------------
__global__ __launch_bounds__(256, 4) void mfma_min_kernel(
    const unsigned short* __restrict__ Apk, const unsigned short* __restrict__ Bpk,
    const float* __restrict__ y2, ull* __restrict__ minpack)
{
    __shared__ __align__(16) unsigned short smem[4 * 128 * 32];  // 32 KB
    const int PAN = 128 * 32;   // 4096 elems = 8 KB panel
    // panels: A0=smem[0], A1=smem[PAN], B0=smem[2*PAN], B1=smem[3*PAN]

    const int tid  = threadIdx.x;
    const int lane = tid & 63;
    const int wave = tid >> 6;
    const int wr = wave >> 1, wc = wave & 1;
    const int n0 = blockIdx.y * 128;
    const int m0 = blockIdx.x * 128;

    const int srow = tid >> 2;   // 0..63 staging base row
    const int sseg = tid & 3;    // 16B segment (LDS phys)
    const int ssw  = sseg ^ ((srow >> 1) & 3);   // swizzled GLOBAL segment

    const int qa = lane >> 4;    // k-quad (logical)
    const int ra = lane & 15;    // row-in-frag / col-in-C
    const int qsw = qa ^ ((ra >> 1) & 3);        // swizzled LDS segment to read

    f32x4 acc[4][4];
    #pragma unroll
    for (int i = 0; i < 4; ++i)
        #pragma unroll
        for (int j = 0; j < 4; ++j)
            acc[i][j] = (f32x4){0.f, 0.f, 0.f, 0.f};

    const unsigned short* gA = Apk + (size_t)(n0 + srow) * KPA + ssw * 8;
    const unsigned short* gB = Bpk + (size_t)(m0 + srow) * KPB + ssw * 8;
    const int lof0 = srow * 32 + sseg * 8;            // linear LDS dests
    const int lof1 = (srow + 64) * 32 + sseg * 8;

    // prologue: A(0) -> A0, B(0) -> B0
    gload_lds16(gA,            &smem[lof0]);
    gload_lds16(gA + 64 * KPA, &smem[lof1]);
    gload_lds16(gB,            &smem[2 * PAN + lof0]);
    gload_lds16(gB + 64 * KPB, &smem[2 * PAN + lof1]);

    #define STEP(s, VM) { \
        /* drain this wave's LDS reads of the buffer we are about to let   */ \
        /* other waves overwrite; sched_barrier pins it (rule #18)         */ \
        asm volatile("s_waitcnt lgkmcnt(0)" ::: "memory"); \
        __builtin_amdgcn_sched_barrier(0); \
        /* barrier#1: all waves done reading the bufs we now overwrite */ \
        asm volatile("s_barrier" ::: "memory"); \
        if ((s) < 3) { \
            const int ko = ((s) + 1) * 32; \
            const int nb = ((s) + 1) & 1; \
            gload_lds16(gA + ko,            &smem[nb * PAN + lof0]); \
            gload_lds16(gA + ko + 64 * KPA, &smem[nb * PAN + lof1]); \
            gload_lds16(gB + ko,            &smem[(2 + nb) * PAN + lof0]); \
            gload_lds16(gB + ko + 64 * KPB, &smem[(2 + nb) * PAN + lof1]); \
        } \
        /* wait: previous step's 4 loads complete; this step's 4 in flight */ \
        asm volatile("s_waitcnt vmcnt(" #VM ")" ::: "memory"); \
        /* barrier#2: current panels complete in every wave */ \
        asm volatile("s_barrier" ::: "memory"); \
        const unsigned short* As = &smem[((s) & 1) * PAN]; \
        const unsigned short* Bs = &smem[(2 + ((s) & 1)) * PAN]; \
        bf16x8 bfr[4]; \
        _Pragma("unroll") \
        for (int j = 0; j < 4; ++j) \
            bfr[j] = *(const bf16x8*)&Bs[(wc * 64 + j * 16 + ra) * 32 + qsw * 8]; \
        { \
            bf16x8 af0 = *(const bf16x8*)&As[(wr * 64 +  0 + ra) * 32 + qsw * 8]; \
            bf16x8 af1 = *(const bf16x8*)&As[(wr * 64 + 16 + ra) * 32 + qsw * 8]; \
            _Pragma("unroll") \
            for (int j = 0; j < 4; ++j) \
                acc[0][j] = __builtin_amdgcn_mfma_f32_16x16x32_bf16(af0, bfr[j], acc[0][j], 0, 0, 0); \
            _Pragma("unroll") \
            for (int j = 0; j < 4; ++j) \
                acc[1][j] = __builtin_amdgcn_mfma_f32_16x16x32_bf16(af1, bfr[j], acc[1][j], 0, 0, 0); \
            __builtin_amdgcn_sched_barrier(0); \
            bf16x8 af2 = *(const bf16x8*)&As[(wr * 64 + 32 + ra) * 32 + qsw * 8]; \
            bf16x8 af3 = *(const bf16x8*)&As[(wr * 64 + 48 + ra) * 32 + qsw * 8]; \
            _Pragma("unroll") \
            for (int j = 0; j < 4; ++j) \
                acc[2][j] = __builtin_amdgcn_mfma_f32_16x16x32_bf16(af2, bfr[j], acc[2][j], 0, 0, 0); \
            _Pragma("unroll") \
            for (int j = 0; j < 4; ++j) \
                acc[3][j] = __builtin_amdgcn_mfma_f32_16x16x32_bf16(af3, bfr[j], acc[3][j], 0, 0, 0); \
        } \
    }

    STEP(0, 4) STEP(1, 4) STEP(2, 4) STEP(3, 0)
    #undef STEP

    // ---- epilogue (R11 proven): key = y2[m]+1000 - 2*dot; pack; reduce ----
    float y2k[4];
    unsigned mj[4];
    #pragma unroll
    for (int j = 0; j < 4; ++j) {
        const int m = m0 + wc * 64 + j * 16 + ra;
        y2k[j] = y2[m] + 1000.0f;
        mj[j]  = (unsigned)m;
    }

    ull (*red2)[32] = (ull (*)[32])smem;   // 128 rows x 32 = 32 KB (whole smem)

    // all waves must be done reading the K-panels before red2 overwrites them
    __syncthreads();

    #pragma unroll
    for (int i = 0; i < 4; ++i) {
        #pragma unroll
        for (int r = 0; r < 4; ++r) {
            const int rowl = wr * 64 + i * 16 + qa * 4 + r;
            ull mn = ~0ull;
            #pragma unroll
            for (int j = 0; j < 4; ++j) {
                float key = fmaf(-2.0f, acc[i][j][r], y2k[j]);   // > 0 always
                ull p = ((ull)__float_as_uint(key) << 32) | mj[j];
                mn = umin64(mn, p);
            }
            red2[rowl][wc * 16 + ra] = mn;
        }
    }
    __syncthreads();
    if (tid < 128) {
        const int l = tid & 63;
        ull mn = ~0ull;
        #pragma unroll
        for (int k = 0; k < 32; ++k)     // lane-staggered cols: distinct bank pairs
            mn = umin64(mn, red2[tid][(k + l) & 31]);
        atomicMin(&minpack[n0 + tid], mn);
    }
}

// ---------------------------------------------------------------------------
// Kernel 2: tiny per-batch argmax (1 block, 256 threads; wave w handles
// batches w and w+4; identical float exprs/packing to the proven reduce).
// ---------------------------------------------------------------------------
__global__ __launch_bounds__(256) void argmax_kernel(
    const ull* __restrict__ minpack, const float* __restrict__ x2,
    float* __restrict__ bscore, int* __restrict__ bmaxp, int* __restrict__ bnn)
{
    const int tid = threadIdx.x;
    const int wv = tid >> 6, ln = tid & 63;
    #pragma unroll
    for (int half = 0; half < 2; ++half) {
        const int bb = wv + half * 4;
        ull best = 0;
        for (int i = ln; i < P_PATCH; i += 64) {
            ull mp = minpack[bb * P_PATCH + i];
            float key = __uint_as_float((unsigned)(mp >> 32));
            float d2 = key - 1000.0f + x2[bb * P_PATCH + i];
            float sc = sqrtf(fmaxf(d2, 0.0f));
            ull pk = ((ull)__float_as_uint(sc) << 32) | (unsigned)(i ^ 0xFFFFFFFFu);
            best = umax64(best, pk);
        }
        #pragma unroll
        for (int s = 1; s < 64; s <<= 1)
            best = umax64(best, (ull)__shfl_xor((unsigned long long)best, s, 64));
        if (ln == 0) {
            int p = (int)(((unsigned)(best & 0xFFFFFFFFu)) ^ 0xFFFFFFFFu);
            bscore[bb] = __uint_as_float((unsigned)(best >> 32));
            bmaxp[bb]  = p;
            bnn[bb]    = (int)(minpack[bb * P_PATCH + p] & 0xFFFFFFFFu);
        }
    }
}

// ---------------------------------------------------------------------------
// Kernel 3: d_nn = dist(nn_sample[b], memory_bank) -> (8, M)
// (8192 blocks, fully parallel, BW-bound; depends only on bnn)
// ---------------------------------------------------------------------------
__global__ __launch_bounds__(256) void dnn_kernel(
    const float* __restrict__ bank, const float* __restrict__ y2,
    const int* __restrict__ bnn, float* __restrict__ dnn)
{
    __shared__ float nn[BATCH][D_DIM];
    __shared__ float nny2[BATCH];
    int tid = threadIdx.x;
    for (int i = tid; i < BATCH * D_DIM; i += 256) {
        int b = i >> 7, d = i & 127;
        nn[b][d] = bank[(size_t)bnn[b] * D_DIM + d];
    }
    if (tid < BATCH) nny2[tid] = y2[bnn[tid]];
    __syncthreads();

    int w = tid >> 6, lane = tid & 63;
    int m = blockIdx.x * 4 + w;
    float2 v = *(const float2*)&bank[(size_t)m * D_DIM + 2 * lane];
    float part[BATCH];
    #pragma unroll
    for (int b = 0; b < BATCH; ++b)
        part[b] = fmaf(v.x, nn[b][2 * lane], v.y * nn[b][2 * lane + 1]);
    #pragma unroll
    for (int b = 0; b < BATCH; ++b) {
        float s = part[b];
        #pragma unroll
        for (int off = 32; off > 0; off >>= 1) s += __shfl_down(s, off, 64);
        if (lane == 0) {
            float d2 = nny2[b] + y2[m] - 2.0f * s;
            dnn[b * M_BANK + m] = sqrtf(fmaxf(d2, 0.0f));
        }
    }
}

// ---------------------------------------------------------------------------
// Kernel 4 (merged blur + topk, proven R15/R16): grid (39, 8). ch<32: per-
// (b,ch) top-9 of d_nn (+ last-block final, 256-block ticket). ch>=32: blur
// band ch-32 for batch b. Block-uniform branch; LDS union.
// ---------------------------------------------------------------------------
__device__ __forceinline__ int refl224(int i) {
    if (i < 0) i = -i;
    if (i >= OUT_WH) i = 2 * (OUT_WH - 1) - i;
    return i;
}

union SharedU {
    struct {
        float g[KSIZE];
        float ps[P_PATCH];
        float q[GRID_WH * OUT_WH];
        float hq[GRID_WH * OUT_WH];
        float wrow[32][GRID_WH];
    } blur;
    struct {
        ull vals[1024];
        ull red[256];
    } topk;
};

__global__ __launch_bounds__(256) void blur_topk_kernel(
    const ull* __restrict__ minpack, const float* __restrict__ x2,
    const float* __restrict__ dnn, ull* __restrict__ cand,
    const float* __restrict__ emb, const float* __restrict__ bank,
    const float* __restrict__ y2,
    const float* __restrict__ bscore, const int* __restrict__ bmaxp,
    float* __restrict__ out)
{
    __shared__ SharedU su;
    __shared__ unsigned lastflag;
    const int tid = threadIdx.x;
    const int b = blockIdx.y;

    if (blockIdx.x < 32) {
        // ---------------- top-9 branch ----------------
        const int ch = blockIdx.x;
        const int base = ch * 1024;
        ull* vals = su.topk.vals;
        ull* red  = su.topk.red;

        #pragma unroll
        for (int j = 0; j < 4; ++j) {
            int i = base + tid + j * 256;
            vals[tid + j * 256] = ((ull)__float_as_uint(dnn[b * M_BANK + i]) << 32) | (unsigned)i;
        }
        __syncthreads();

        for (int k = 0; k < KNN; ++k) {
            ull local = vals[tid];
            #pragma unroll
            for (int j = 1; j < 4; ++j) local = umin64(local, vals[tid + j * 256]);
            red[tid] = local;
            __syncthreads();
            for (int s = 128; s > 0; s >>= 1) {
                if (tid < s) red[tid] = umin64(red[tid], red[tid + s]);
                __syncthreads();
            }
            ull win = red[0];
            if (tid == 0) cand[(b * 32 + ch) * KNN + k] = win;
            #pragma unroll
            for (int j = 0; j < 4; ++j)
                if (vals[tid + j * 256] == win) vals[tid + j * 256] = ~0ull;
            __syncthreads();
        }

        // ---- last-block final phase (ticket over 256 topk blocks) ----
        if (tid == 0) {
            __threadfence();                   // publish this block's cand
            unsigned t = atomicAdd(&tpf_ctr, 1u);
            lastflag = (t == 8u * 32u - 1u);
        }
        __syncthreads();
        if (!lastflag) return;
        __threadfence();                       // acquire all blocks' cand

        const int wv = tid >> 6, ln = tid & 63;
        #pragma unroll
        for (int half = 0; half < 2; ++half) {
            const int bb = wv + half * 4;
            const ull* cb = cand + (size_t)bb * 32 * KNN;   // 288 candidates
            ull c0 = cb[ln];
            ull c1 = cb[ln + 64];
            ull c2 = cb[ln + 128];
            ull c3 = cb[ln + 192];
            ull c4 = (ln < 32) ? cb[ln + 256] : ~0ull;
            const int e = bb * P_PATCH + bmaxp[bb];
            const float mf0 = emb[(size_t)e * D_DIM + 2 * ln];
            const float mf1 = emb[(size_t)e * D_DIM + 2 * ln + 1];
            const float xe = x2[e];
            float dists[KNN];
            #pragma unroll
            for (int k = 0; k < KNN; ++k) {
                ull mn = umin64(umin64(umin64(c0, c1), umin64(c2, c3)), c4);
                #pragma unroll
                for (int s = 1; s < 64; s <<= 1)
                    mn = umin64(mn, (ull)__shfl_xor((unsigned long long)mn, s, 64));
                if (c0 == mn) c0 = ~0ull;
                if (c1 == mn) c1 = ~0ull;
                if (c2 == mn) c2 = ~0ull;
                if (c3 == mn) c3 = ~0ull;
                if (c4 == mn) c4 = ~0ull;
                const int m = (int)(mn & 0xFFFFFFFFu);
                float dot = fmaf(mf0, bank[(size_t)m * D_DIM + 2 * ln],
                                 mf1 * bank[(size_t)m * D_DIM + 2 * ln + 1]);
                #pragma unroll
                for (int s = 1; s < 64; s <<= 1)
                    dot += __shfl_xor(dot, s, 64);
                float d2 = xe - 2.0f * dot + y2[m];
                dists[k] = sqrtf(fmaxf(d2, 0.0f));
            }
            if (ln == 0) {
                float mx = dists[0];
                #pragma unroll
                for (int k = 1; k < KNN; ++k) mx = fmaxf(mx, dists[k]);
                float ssum = 0.0f;
                #pragma unroll
                for (int k = 0; k < KNN; ++k) ssum += expf(dists[k] - mx);
                float wgt = 1.0f - expf(dists[0] - mx) / ssum;
                out[bb] = wgt * bscore[bb];
            }
        }
        if (tid == 0) atomicExch(&tpf_ctr, 0u);    // reset for next replay
        return;
    }

    // ---------------- blur branch ----------------
    const int band = blockIdx.x - 32;     // 0..6
    float* g    = su.blur.g;
    float* ps   = su.blur.ps;
    float* q    = su.blur.q;
    float* hq   = su.blur.hq;
    float (*wrow)[GRID_WH] = su.blur.wrow;
    float* outp = out + BATCH;

    if (tid < KSIZE) {
        float x = (tid - KRAD) * 0.25f;
        g[tid] = __expf(-0.5f * x * x);
    }
    for (int i = tid; i < P_PATCH; i += 256) {
        ull mp = minpack[b * P_PATCH + i];
        float key = __uint_as_float((unsigned)(mp >> 32));
        float d2 = key - 1000.0f + x2[b * P_PATCH + i];
        ps[i] = sqrtf(fmaxf(d2, 0.0f));
    }
    __syncthreads();
    if (tid == 0) {
        float s = 0.0f;
        for (int i = 0; i < KSIZE; ++i) s += g[i];
        float inv = 1.0f / s;
        for (int i = 0; i < KSIZE; ++i) g[i] *= inv;
    }
    __syncthreads();

    for (int i = tid; i < GRID_WH * OUT_WH; i += 256) {
        int gy = i / OUT_WH, x = i - gy * OUT_WH;
        float cx = (2 * x - 7) * 0.0625f;
        int ix = (int)floorf(cx); float fx = cx - ix;
        int x0 = min(max(ix, 0), GRID_WH - 1), x1 = min(max(ix + 1, 0), GRID_WH - 1);
        q[i] = ps[gy * GRID_WH + x0] * (1.0f - fx) + ps[gy * GRID_WH + x1] * fx;
    }

    if (tid < 32) {
        int y = band * 32 + tid;
        for (int gy = 0; gy < GRID_WH; ++gy) wrow[tid][gy] = 0.0f;
        for (int t = 0; t < KSIZE; ++t) {
            int yy = refl224(y - KRAD + t);
            float cy = (2 * yy - 7) * 0.0625f;
            int iy = (int)floorf(cy); float fy = cy - iy;
            int y0 = min(max(iy, 0), GRID_WH - 1), y1 = min(max(iy + 1, 0), GRID_WH - 1);
            wrow[tid][y0] += g[t] * (1.0f - fy);
            wrow[tid][y1] += g[t] * fy;
        }
    }
    __syncthreads();

    for (int i = tid; i < GRID_WH * OUT_WH; i += 256) {
        int gy = i / OUT_WH, x = i - gy * OUT_WH;
        float s = 0.0f;
        #pragma unroll
        for (int t = 0; t < KSIZE; ++t)
            s = fmaf(g[t], q[gy * OUT_WH + refl224(x - KRAD + t)], s);
        hq[i] = s;
    }
    __syncthreads();

    const int yl = tid >> 3;                 // 0..31
    const int xbase = (tid & 7) * 28;        // 8 groups x 28 px = 224
    const int y = band * 32 + yl;
    float* orow = outp + ((size_t)b * OUT_WH + y) * OUT_WH;
    for (int i = 0; i < 28; ++i) {
        int x = xbase + i;
        float s = 0.0f;
        #pragma unroll
        for (int gy = 0; gy < GRID_WH; ++gy)
            s = fmaf(wrow[yl][gy], hq[gy * OUT_WH + x], s);
        orow[x] = s;
    }
}

// ---------------------------------------------------------------------------
extern "C" void kernel_launch(void* const* d_in, const int* in_sizes, int n_in,
                              void* d_out, int out_size, void* d_ws, size_t ws_size,
                              hipStream_t stream) {
    const float* emb  = (const float*)d_in[0];
    const float* bank = (const float*)d_in[1];
    float* out = (float*)d_out;

    char* ws = (char*)d_ws;
    ull*   minpack = (ull*)(ws + WS_MINPACK);
    float* x2      = (float*)(ws + WS_X2);
    float* y2      = (float*)(ws + WS_Y2);
    float* bscore  = (float*)(ws + WS_BSCORE);
    int*   bmaxp   = (int*)(ws + WS_BMAXP);
    int*   bnn     = (int*)(ws + WS_BNN);
    float* dnn     = (float*)(ws + WS_DNN);
    unsigned short* Apk = (unsigned short*)(ws + WS_APK);
    unsigned short* Bpk = (unsigned short*)(ws + WS_BPK);
    ull*   cand    = (ull*)(ws + WS_CAND);

    // 0: bf16 pack + sumsq + minpack init (one wave per row)
    prep_kernel<<<(N_EMB + M_BANK) / 4, 256, 0, stream>>>(emb, bank, Apk, Bpk, x2, y2, minpack);
    // 1: MFMA distance + fused min/argmin (R14/R16-proven)
    {
        dim3 grid(M_BANK / 128, N_EMB / 128);   // 256 x 49
        mfma_min_kernel<<<grid, 256, 0, stream>>>(Apk, Bpk, y2, minpack);
    }
    // 2: tiny per-batch argmax (1 block) -> bscore/bmaxp/bnn
    argmax_kernel<<<1, 256, 0, stream>>>(minpack, x2, bscore, bmaxp, bnn);
    // 3: d_nn (8192 blocks, fully parallel)
    dnn_kernel<<<M_BANK / 4, 256, 0, stream>>>(bank, y2, bnn, dnn);
    // 4: merged blur (bands) + per-chunk top-9 + last-block final -> out
    {
        dim3 grid(32 + OUT_WH / 32, BATCH);     // 39 x 8
        blur_topk_kernel<<<grid, 256, 0, stream>>>(minpack, x2, dnn, cand, emb, bank, y2, bscore, bmaxp, out);
    }
}